// Round 16
// baseline (194.003 us; speedup 1.0000x reference)
//
#include <hip/hip_runtime.h>
#include <cstdint>
#include <cstddef>

#define TSEQ 2048
#define DMOD 1024
#define NHEAD 16
#define NBATCH 2
#define MT (NBATCH * TSEQ)
#define LOG2E 1.44269504088896340736f

typedef __attribute__((ext_vector_type(8))) __bf16 bf16x8;
typedef __attribute__((ext_vector_type(4))) float f32x4;
typedef __attribute__((ext_vector_type(8))) unsigned short u16x8;
typedef __attribute__((ext_vector_type(4))) unsigned short u16x4;
typedef __attribute__((ext_vector_type(4))) uint32_t u32x4;

__device__ __forceinline__ unsigned short f2bf(float f) {
  uint32_t u = __builtin_bit_cast(uint32_t, f);
  u += 0x7fffu + ((u >> 16) & 1u);   // RNE (inputs finite)
  return (unsigned short)(u >> 16);
}

__device__ __forceinline__ uint32_t cvt_pk_bf16(float a, float b) {
  uint32_t r;
  asm("v_cvt_pk_bf16_f32 %0, %1, %2" : "=v"(r) : "v"(a), "v"(b));
  return r;
}

__device__ __forceinline__ void gload_lds16(const void* g, const void* l) {
  auto gp = (const __attribute__((address_space(1))) uint32_t*)((uintptr_t)g);
  auto lp = (__attribute__((address_space(3))) uint32_t*)((uintptr_t)l);
  __builtin_amdgcn_global_load_lds(gp, lp, 16, 0, 0);
}

// ------- merged: weight fp32->bf16 cvt (blocks 0..4095) + mask expand ------
__global__ __launch_bounds__(256) void cvt_wm(const float* __restrict__ w0,
                                              const float* __restrict__ w1,
                                              const float* __restrict__ w2,
                                              const float* __restrict__ w3,
                                              const int* __restrict__ m,
                                              unsigned short* __restrict__ dw,
                                              uint32_t* __restrict__ mx) {
  const int bx = blockIdx.x;
  if (bx < 4096) {
    const size_t idx = ((size_t)bx * 256 + threadIdx.x) * 4;   // 4 weights x 1M elems
    const int wsel = (int)(idx >> 20);
    const float* s = wsel == 0 ? w0 : (wsel == 1 ? w1 : (wsel == 2 ? w2 : w3));
    const float4 t = *(const float4*)(s + (idx & 0xFFFFFu));
    u16x4 o;
    o[0] = f2bf(t.x); o[1] = f2bf(t.y); o[2] = f2bf(t.z); o[3] = f2bf(t.w);
    *(u16x4*)(dw + idx) = o;
  } else {
    const size_t W = (size_t)(bx - 4096) * 256 + threadIdx.x;  // < 2*T*16*32
    const int hi = (int)((W >> 3) & 3), ct = (int)(W & 7);
    const size_t bqkt = W >> 5;
    const int kt = (int)(bqkt & 15);
    const size_t bq = bqkt >> 4;
    const int4 mm = *(const int4*)(m + bq * TSEQ + kt * 128 + ct * 16 + hi * 4);
    const uint32_t o = (mm.x ? 0xFFu : 0u) | (mm.y ? 0xFF00u : 0u) |
                       (mm.z ? 0xFF0000u : 0u) | (mm.w ? 0xFF000000u : 0u);
    mx[W] = o;
  }
}

// ---------------- GEMM: C = A[M x 1024] * W[1024x1024]^T + bias, *scale ----
// BK=64 (round-15 config, frozen): 32 MFMA per barrier, 16 barriers, XOR-swz.
__device__ __forceinline__ void store_c(unsigned short* C, size_t idx, float v) { C[idx] = f2bf(v); }
__device__ __forceinline__ void store_c(float* C, size_t idx, float v) { C[idx] = v; }

template <typename OT, int MF, bool AF32>
__global__ __launch_bounds__(256) void gemm_bt(const void* __restrict__ A0v,
                                               const void* __restrict__ A1v,
                                               const void* __restrict__ A2v,
                                               const unsigned short* __restrict__ W0,
                                               const unsigned short* __restrict__ W1,
                                               const unsigned short* __restrict__ W2,
                                               const float* __restrict__ b0,
                                               const float* __restrict__ b1,
                                               const float* __restrict__ b2,
                                               OT* __restrict__ C0, OT* __restrict__ C1, OT* __restrict__ C2,
                                               float s0, float s1, float s2) {
  constexpr int BM = MF * 32;
  constexpr int NX = 4096 / BM;          // x-tiles per z
  const int nb = gridDim.x, per = nb >> 3, bid = blockIdx.x;
  const int swz = (bid & 7) * per + (bid >> 3);
  const int z = swz / (NX * 8);
  const int rem = swz % (NX * 8);
  const int m0 = (rem >> 3) * BM, n0 = (rem & 7) * 128;

  const void* Av = z == 0 ? A0v : (z == 1 ? A1v : A2v);
  const unsigned short* Bw = z == 0 ? W0 : (z == 1 ? W1 : W2);
  const float* bias = z == 0 ? b0 : (z == 1 ? b1 : b2);
  OT* C = z == 0 ? C0 : (z == 1 ? C1 : C2);
  const float scale = z == 0 ? s0 : (z == 1 ? s1 : s2);

  __shared__ alignas(16) unsigned short As[2][BM * 64];    // [row][64] swizzled
  __shared__ alignas(16) unsigned short Bs[2][128 * 64];   // [row][64] swizzled
  const int tid = threadIdx.x;
  const int wid = tid >> 6;
  const int lane = tid & 63;
  const int lo = lane & 15, hi = lane >> 4;
  const int wr = wid >> 1, wc = wid & 1;
  f32x4 acc[MF][4] = {};

  float4 fa[MF][2];   // A reg-staging (AF32 only)

  auto loadA = [&](int k0) {
    if constexpr (AF32) {
#pragma unroll
      for (int j = 0; j < MF; ++j) {
        const int chunk = j * 256 + tid;
        const int row = chunk >> 3, cl = (chunk & 7) ^ (row & 7);
        const float* p = (const float*)Av + (size_t)(m0 + row) * DMOD + k0 + cl * 8;
        fa[j][0] = *(const float4*)p;
        fa[j][1] = *(const float4*)(p + 4);
      }
    }
  };
  auto writeA = [&](int buf) {
    if constexpr (AF32) {
#pragma unroll
      for (int j = 0; j < MF; ++j) {
        const int chunk = j * 256 + tid;
        u32x4 o;
        o[0] = cvt_pk_bf16(fa[j][0].x, fa[j][0].y);
        o[1] = cvt_pk_bf16(fa[j][0].z, fa[j][0].w);
        o[2] = cvt_pk_bf16(fa[j][1].x, fa[j][1].y);
        o[3] = cvt_pk_bf16(fa[j][1].z, fa[j][1].w);
        *(u32x4*)((char*)As + buf * (BM * 128) + chunk * 16) = o;
      }
    }
  };
  auto stage = [&](int buf, int k0) {
    if constexpr (!AF32) {
#pragma unroll
      for (int i = 0; i < MF; ++i) {
        const int chunk = i * 256 + tid;
        const int row = chunk >> 3, cl = (chunk & 7) ^ (row & 7);
        gload_lds16((const unsigned short*)Av + (size_t)(m0 + row) * DMOD + k0 + cl * 8,
                    (const char*)As + buf * (BM * 128) + chunk * 16);
      }
    }
#pragma unroll
    for (int i = 0; i < 4; ++i) {
      const int chunk = i * 256 + tid;
      const int row = chunk >> 3, cl = (chunk & 7) ^ (row & 7);
      gload_lds16(Bw + (size_t)(n0 + row) * DMOD + k0 + cl * 8,
                  (const char*)Bs + buf * 16384 + chunk * 16);
    }
  };

  loadA(0);
  writeA(0);
  stage(0, 0);
  __syncthreads();    // K-step 0 landed

  for (int k0 = 0; k0 < DMOD; k0 += 64) {
    const int cur = (k0 >> 6) & 1;
    const bool more = k0 + 64 < DMOD;
    if (more) { loadA(k0 + 64); stage(cur ^ 1, k0 + 64); }

#pragma unroll
    for (int kk = 0; kk < 2; ++kk) {
      bf16x8 af[MF], bfr[4];
#pragma unroll
      for (int m = 0; m < MF; ++m) {
        const int row = wr * (MF * 16) + m * 16 + lo;
        af[m] = *(const bf16x8*)((const char*)As + cur * (BM * 128) +
                                 row * 128 + (((kk * 4 + hi) ^ (lo & 7)) * 16));
      }
#pragma unroll
      for (int n = 0; n < 4; ++n) {
        const int row = wc * 64 + n * 16 + lo;
        bfr[n] = *(const bf16x8*)((const char*)Bs + cur * 16384 +
                                  row * 128 + (((kk * 4 + hi) ^ (lo & 7)) * 16));
      }
#pragma unroll
      for (int m = 0; m < MF; ++m)
#pragma unroll
        for (int n = 0; n < 4; ++n)
          acc[m][n] = __builtin_amdgcn_mfma_f32_16x16x32_bf16(af[m], bfr[n], acc[m][n], 0, 0, 0);
    }

    if (more) writeA(cur ^ 1);
    __syncthreads();
  }

#pragma unroll
  for (int n = 0; n < 4; ++n) {
    const int col = n0 + wc * 64 + n * 16 + lo;
    const float bv = bias[col];
#pragma unroll
    for (int m = 0; m < MF; ++m) {
      const int row = m0 + wr * (MF * 16) + m * 16 + hi * 4;
#pragma unroll
      for (int r = 0; r < 4; ++r)
        store_c(C, (size_t)(row + r) * DMOD + col, (acc[m][n][r] + bv) * scale);
    }
  }
}

// ---------------- V transpose + nu-permute: Vp[B*T][D] -> Vt'[...][nu(t)] ---
__global__ __launch_bounds__(256) void transpose_v(const unsigned short* __restrict__ Vp,
                                                   unsigned short* __restrict__ Vt) {
  __shared__ alignas(16) unsigned short tile[64][72];
  const int tid = threadIdx.x;
  const int bt0 = blockIdx.x * 64;
  const int h = blockIdx.y;
  const int b = bt0 >> 11;
  const int t0 = bt0 & (TSEQ - 1);
#pragma unroll
  for (int i = 0; i < 2; ++i) {
    const int chunk = i * 256 + tid;
    const int row = chunk >> 3, c = chunk & 7;
    *(uint4*)((char*)&tile[row][0] + c * 16) =
        *(const uint4*)(Vp + (size_t)(bt0 + row) * DMOD + h * 64 + c * 8);
  }
  __syncthreads();
#pragma unroll
  for (int i = 0; i < 2; ++i) {
    const int chunk = i * 256 + tid;
    const int dk = chunk >> 3, c = chunk & 7;
    u16x8 o;
#pragma unroll
    for (int j = 0; j < 8; ++j) {
      const int x = c * 8 + j;   // nu index within the 64-tile
      const int kl = (x & 32) | ((x & 24) >> 1) | ((x & 4) << 2) | (x & 3);
      o[j] = tile[kl][dk];
    }
    *(u16x8*)(Vt + ((size_t)(b * NHEAD + h) * 64 + dk) * TSEQ + t0 + c * 8) = o;
  }
}

// -------- flash attention: T15 double-pipeline via MACROS (no pointers) ----
// QK(t+1) on the MFMA pipe overlaps exp/pack/PV(t) on the VALU/TRANS pipes.
// sA/sB are named arrays, all indices compile-time (rule #20 safe).
// K 2-buf, V 3-buf (stage(t+2) never clobbers the V being consumed). 80 KB.
__global__ __launch_bounds__(512, 4) void attn_kernel(const unsigned short* __restrict__ Qp,
                                                      const unsigned short* __restrict__ Kp,
                                                      const unsigned short* __restrict__ Vt,
                                                      const uint32_t* __restrict__ mx,
                                                      unsigned short* __restrict__ AO) {
  __shared__ alignas(16) unsigned short Ks[2][128 * 64];   // [kcol][d] chunk-XOR swizzled
  __shared__ alignas(16) unsigned short Vs[3][64 * 128];   // [dk][nu]  chunk-XOR swizzled
  const int tid = threadIdx.x;
  const int w = tid >> 6, lane = tid & 63;
  const int lo = lane & 15, hi = lane >> 4;
  const int f = blockIdx.x;                 // 0..511, XCD swizzle
  const int swz = (f & 7) * 64 + (f >> 3);
  const int q0 = (swz & 15) * 128;
  const int h = (swz >> 4) & 15;
  const int b = swz >> 8;

  bf16x8 qf[2];
  {
    const unsigned short* qsrc =
        Qp + (size_t)(b * TSEQ + q0 + w * 16 + lo) * DMOD + h * 64 + hi * 8;
    qf[0] = *(const bf16x8*)qsrc;
    qf[1] = *(const bf16x8*)(qsrc + 32);
  }

  bf16x8 ones;
  {
    u32x4 od;
    od[0] = 0x3F803F80u; od[1] = 0x3F803F80u; od[2] = 0x3F803F80u; od[3] = 0x3F803F80u;
    ones = __builtin_bit_cast(bf16x8, od);
  }

  f32x4 o_acc[4] = {};
  f32x4 l_acc = {};

  const size_t kbase = (size_t)(b * TSEQ) * DMOD + h * 64;
  const size_t vbase = (size_t)(b * NHEAD + h) * 64 * TSEQ;

  const int c0 = tid, c1 = 512 + tid;
  const unsigned short* kp0 = Kp + kbase + (size_t)(c0 >> 3) * DMOD + ((c0 & 7) ^ ((c0 >> 3) & 7)) * 8;
  const unsigned short* kp1 = Kp + kbase + (size_t)(c1 >> 3) * DMOD + ((c1 & 7) ^ ((c1 >> 3) & 7)) * 8;
  const unsigned short* vp0 = Vt + vbase + (size_t)(c0 >> 4) * TSEQ + ((c0 & 15) ^ ((c0 >> 4) & 7)) * 8;
  const unsigned short* vp1 = Vt + vbase + (size_t)(c1 >> 4) * TSEQ + ((c1 & 15) ^ ((c1 >> 4) & 7)) * 8;
  const uint32_t* mp = mx + (size_t)(b * TSEQ + q0 + w * 16 + lo) * 512 + hi * 8;
  const int wb0 = c0 * 16, wb1 = c1 * 16;

  int koffA[8], koffB[8];
#pragma unroll
  for (int ct = 0; ct < 8; ++ct) {
    const int kcol = ct * 16 + lo;
    koffA[ct] = kcol * 128 + ((hi ^ (kcol & 7)) * 16);
    koffB[ct] = kcol * 128 + (((4 + hi) ^ (kcol & 7)) * 16);
  }
  int voff[4][4];
#pragma unroll
  for (int vt = 0; vt < 4; ++vt) {
    const int dk = vt * 16 + lo;
#pragma unroll
    for (int c = 0; c < 4; ++c) voff[vt][c] = dk * 256 + (((c * 4 + hi) ^ (dk & 7)) * 16);
  }

  auto stage = [&](int kbuf, int vbuf) {
    gload_lds16(kp0, (const char*)Ks[kbuf] + wb0);
    gload_lds16(kp1, (const char*)Ks[kbuf] + wb1);
    gload_lds16(vp0, (const char*)Vs[vbuf] + wb0);
    gload_lds16(vp1, (const char*)Vs[vbuf] + wb1);
    kp0 += (size_t)128 * DMOD; kp1 += (size_t)128 * DMOD;
    vp0 += 128; vp1 += 128;
  };

  const uint32_t selA = 0x01010000u, selB = 0x03030202u;

#define QK_TILE(S, KSB) do {                                                  \
    const char* _k = (KSB);                                                   \
    __builtin_amdgcn_s_setprio(1);                                            \
    _Pragma("unroll")                                                         \
    for (int ct = 0; ct < 8; ++ct) {                                          \
      bf16x8 kf0 = *(const bf16x8*)(_k + koffA[ct]);                          \
      bf16x8 kf1 = *(const bf16x8*)(_k + koffB[ct]);                          \
      f32x4 zz = {0.f, 0.f, 0.f, 0.f};                                        \
      S[ct] = __builtin_amdgcn_mfma_f32_16x16x32_bf16(kf0, qf[0], zz, 0, 0, 0);    \
      S[ct] = __builtin_amdgcn_mfma_f32_16x16x32_bf16(kf1, qf[1], S[ct], 0, 0, 0); \
    }                                                                         \
    __builtin_amdgcn_s_setprio(0);                                            \
  } while (0)

#define EXPPV_TILE(S, M0, M1, VSB) do {                                       \
    const char* _v = (VSB);                                                   \
    _Pragma("unroll")                                                         \
    for (int ct = 0; ct < 8; ++ct) {                                          \
      S[ct][0] = __builtin_exp2f(S[ct][0]);                                   \
      S[ct][1] = __builtin_exp2f(S[ct][1]);                                   \
      S[ct][2] = __builtin_exp2f(S[ct][2]);                                   \
      S[ct][3] = __builtin_exp2f(S[ct][3]);                                   \
    }                                                                         \
    bf16x8 pf[4];                                                             \
    _Pragma("unroll")                                                         \
    for (int c = 0; c < 4; ++c) {                                             \
      const uint32_t We = c == 0 ? M0.x : (c == 1 ? M0.z : (c == 2 ? M1.x : M1.z)); \
      const uint32_t Wo = c == 0 ? M0.y : (c == 1 ? M0.w : (c == 2 ? M1.y : M1.w)); \
      u32x4 pd;                                                               \
      pd[0] = cvt_pk_bf16(S[2 * c][0], S[2 * c][1]) & __builtin_amdgcn_perm(We, We, selA); \
      pd[1] = cvt_pk_bf16(S[2 * c][2], S[2 * c][3]) & __builtin_amdgcn_perm(We, We, selB); \
      pd[2] = cvt_pk_bf16(S[2 * c + 1][0], S[2 * c + 1][1]) & __builtin_amdgcn_perm(Wo, Wo, selA); \
      pd[3] = cvt_pk_bf16(S[2 * c + 1][2], S[2 * c + 1][3]) & __builtin_amdgcn_perm(Wo, Wo, selB); \
      pf[c] = __builtin_bit_cast(bf16x8, pd);                                 \
    }                                                                         \
    __builtin_amdgcn_s_setprio(1);                                            \
    _Pragma("unroll")                                                         \
    for (int vt = 0; vt < 4; ++vt) {                                          \
      _Pragma("unroll")                                                       \
      for (int c = 0; c < 4; ++c) {                                           \
        bf16x8 vf = *(const bf16x8*)(_v + voff[vt][c]);                       \
        o_acc[vt] = __builtin_amdgcn_mfma_f32_16x16x32_bf16(pf[c], vf, o_acc[vt], 0, 0, 0); \
      }                                                                       \
    }                                                                         \
    _Pragma("unroll")                                                         \
    for (int c = 0; c < 4; ++c)                                               \
      l_acc = __builtin_amdgcn_mfma_f32_16x16x32_bf16(pf[c], ones, l_acc, 0, 0, 0); \
    __builtin_amdgcn_s_setprio(0);                                            \
  } while (0)

  const int NT = TSEQ / 128;   // 16 (even)
  f32x4 sA[8], sB[8];
  uint4 mA0, mA1, mB0, mB1;

  // prologue
  mA0 = *(const uint4*)mp; mA1 = *(const uint4*)(mp + 4); mp += 32;
  stage(0, 0);
  __syncthreads();                       // tile 0 landed
  mB0 = *(const uint4*)mp; mB1 = *(const uint4*)(mp + 4); mp += 32;
  stage(1, 1);                           // prefetch tile 1
  QK_TILE(sA, (const char*)Ks[0]);       // scores(tile 0) while tile 1 lands
  __syncthreads();                       // tile 1 landed

  for (int kt = 0; kt < NT; kt += 2) {
    // phase 1: QK(kt+1) || EXPPV(kt)
    uint4 tA0, tA1;
    if (kt + 2 < NT) {
      tA0 = *(const uint4*)mp; tA1 = *(const uint4*)(mp + 4); mp += 32;
      stage(kt & 1, (kt + 2) % 3);       // tile kt+2 -> K[kt&1] (kt's K done), V[(kt+2)%3]
    }
    QK_TILE(sB, (const char*)Ks[(kt + 1) & 1]);
    EXPPV_TILE(sA, mA0, mA1, (const char*)Vs[kt % 3]);
    __syncthreads();                     // tile kt+2 landed; K[kt&1] reads all done
    if (kt + 2 < NT) { mA0 = tA0; mA1 = tA1; }

    // phase 2: QK(kt+2) || EXPPV(kt+1)
    uint4 tB0, tB1;
    if (kt + 3 < NT) {
      tB0 = *(const uint4*)mp; tB1 = *(const uint4*)(mp + 4); mp += 32;
      stage((kt + 1) & 1, (kt + 3) % 3); // tile kt+3 -> K[(kt+1)&1], V[(kt+3)%3]
    }
    if (kt + 2 < NT) QK_TILE(sA, (const char*)Ks[(kt + 2) & 1]);
    EXPPV_TILE(sB, mB0, mB1, (const char*)Vs[(kt + 1) % 3]);
    __syncthreads();                     // tile kt+3 landed
    if (kt + 3 < NT) { mB0 = tB0; mB1 = tB1; }
  }

#undef QK_TILE
#undef EXPPV_TILE

#pragma unroll
  for (int r = 0; r < 4; ++r) {
    const float rl = 1.0f / l_acc[r];
    const size_t orow = (size_t)(b * TSEQ + q0 + w * 16 + hi * 4 + r) * DMOD + h * 64;
#pragma unroll
    for (int vt = 0; vt < 4; ++vt)
      AO[orow + vt * 16 + lo] = f2bf(o_acc[vt][r] * rl);
  }
}

// ---------------- launcher -------------------------------------------------
extern "C" void kernel_launch(void* const* d_in, const int* in_sizes, int n_in,
                              void* d_out, int out_size, void* d_ws, size_t ws_size,
                              hipStream_t stream) {
  const float* q  = (const float*)d_in[0];
  const float* k  = (const float*)d_in[1];
  const float* v  = (const float*)d_in[2];
  const int* mask = (const int*)d_in[3];
  const float* Wq = (const float*)d_in[4];
  const float* bq = (const float*)d_in[5];
  const float* Wk = (const float*)d_in[6];
  const float* bk = (const float*)d_in[7];
  const float* Wv = (const float*)d_in[8];
  const float* bv = (const float*)d_in[9];
  const float* Wo = (const float*)d_in[10];
  const float* bo = (const float*)d_in[11];
  float* out = (float*)d_out;

  char* ws = (char*)d_ws;
  const size_t SZ_BT = (size_t)MT * DMOD * 2;   // 8 MiB

  unsigned short* Qp  = (unsigned short*)(ws + 0);
  unsigned short* Kp  = (unsigned short*)(ws + SZ_BT);
  unsigned short* Vp  = (unsigned short*)(ws + 2 * SZ_BT);
  unsigned short* Vt  = (unsigned short*)(ws + 3 * SZ_BT);
  unsigned short* Wqb = (unsigned short*)(ws + 4 * SZ_BT);          // 4 weights, 8 MiB
  uint32_t*       mx  = (uint32_t*)(ws + 5 * SZ_BT);                // 8.39 MiB
  unsigned short* AO  = Vp;   // Vp dead after transpose_v
  unsigned short* Wob = Wqb + 3 * DMOD * DMOD;

  const int nW = DMOD * DMOD;

  // weights cvt + mask expand, one launch (both memory-bound streams)
  cvt_wm<<<dim3(4096 + (NBATCH * TSEQ * 16 * 32) / 256), 256, 0, stream>>>(
      Wq, Wk, Wv, Wo, mask, Wqb, mx);

  const float qs = 0.125f * LOG2E;
  // QKV projections: fp32 A read directly from inputs, cvt fused into staging
  gemm_bt<unsigned short, 4, true><<<dim3(768), 256, 0, stream>>>(
      q, k, v, Wqb, Wqb + nW, Wqb + 2 * nW, bq, bk, bv, Qp, Kp, Vp, qs, 1.0f, 1.0f);

  transpose_v<<<dim3(MT / 64, NHEAD), 256, 0, stream>>>(Vp, Vt);

  attn_kernel<<<dim3(512), 512, 0, stream>>>(Qp, Kp, Vt, mx, AO);

  gemm_bt<float, 2, false><<<dim3(512), 256, 0, stream>>>(
      AO, AO, AO, Wob, Wob, Wob, bo, bo, bo, out, out, out, 1.0f, 1.0f, 1.0f);
}

// Round 17
// 142.181 us; speedup vs baseline: 1.3645x; 1.3645x over previous
//
#include <hip/hip_runtime.h>
#include <cstdint>
#include <cstddef>

#define TSEQ 2048
#define DMOD 1024
#define NHEAD 16
#define NBATCH 2
#define MT (NBATCH * TSEQ)
#define LOG2E 1.44269504088896340736f

typedef __attribute__((ext_vector_type(8))) __bf16 bf16x8;
typedef __attribute__((ext_vector_type(4))) float f32x4;
typedef __attribute__((ext_vector_type(8))) unsigned short u16x8;
typedef __attribute__((ext_vector_type(4))) unsigned short u16x4;
typedef __attribute__((ext_vector_type(4))) uint32_t u32x4;

__device__ __forceinline__ unsigned short f2bf(float f) {
  uint32_t u = __builtin_bit_cast(uint32_t, f);
  u += 0x7fffu + ((u >> 16) & 1u);   // RNE (inputs finite)
  return (unsigned short)(u >> 16);
}

__device__ __forceinline__ uint32_t cvt_pk_bf16(float a, float b) {
  uint32_t r;
  asm("v_cvt_pk_bf16_f32 %0, %1, %2" : "=v"(r) : "v"(a), "v"(b));
  return r;
}

__device__ __forceinline__ void gload_lds16(const void* g, const void* l) {
  auto gp = (const __attribute__((address_space(1))) uint32_t*)((uintptr_t)g);
  auto lp = (__attribute__((address_space(3))) uint32_t*)((uintptr_t)l);
  __builtin_amdgcn_global_load_lds(gp, lp, 16, 0, 0);
}

// ---------------- weights fp32 -> bf16 (mask moved into QKV GEMM) ----------
__global__ __launch_bounds__(256) void cvt_w(const float* __restrict__ w0,
                                             const float* __restrict__ w1,
                                             const float* __restrict__ w2,
                                             const float* __restrict__ w3,
                                             unsigned short* __restrict__ dw) {
  const size_t idx = ((size_t)blockIdx.x * 256 + threadIdx.x) * 4;   // 4 weights x 1M
  const int wsel = (int)(idx >> 20);
  const float* s = wsel == 0 ? w0 : (wsel == 1 ? w1 : (wsel == 2 ? w2 : w3));
  const float4 t = *(const float4*)(s + (idx & 0xFFFFFu));
  u16x4 o;
  o[0] = f2bf(t.x); o[1] = f2bf(t.y); o[2] = f2bf(t.z); o[3] = f2bf(t.w);
  *(u16x4*)(dw + idx) = o;
}

// ---------------- GEMM: C = A[M x 1024] * W[1024x1024]^T + bias, *scale ----
// BK=64 (round-15 config): 32 MFMA per barrier, 16 barriers, XOR-swizzled LDS.
// AF32: A fp32 direct from inputs, reg-staged with fused cvt_pk (write-late).
// MEXP: this launch also expands the attention mask into byte-masks (mx) —
// 11 guarded load/expand/store iterations per thread, issued in the prologue
// where the latency-bound GEMM has idle VMEM slots. Grid unchanged (768).
__device__ __forceinline__ void store_c(unsigned short* C, size_t idx, float v) { C[idx] = f2bf(v); }
__device__ __forceinline__ void store_c(float* C, size_t idx, float v) { C[idx] = v; }

template <typename OT, int MF, bool AF32, bool MEXP>
__global__ __launch_bounds__(256) void gemm_bt(const void* __restrict__ A0v,
                                               const void* __restrict__ A1v,
                                               const void* __restrict__ A2v,
                                               const unsigned short* __restrict__ W0,
                                               const unsigned short* __restrict__ W1,
                                               const unsigned short* __restrict__ W2,
                                               const float* __restrict__ b0,
                                               const float* __restrict__ b1,
                                               const float* __restrict__ b2,
                                               OT* __restrict__ C0, OT* __restrict__ C1, OT* __restrict__ C2,
                                               float s0, float s1, float s2,
                                               const int* __restrict__ mmask,
                                               uint32_t* __restrict__ mxout) {
  constexpr int BM = MF * 32;
  constexpr int NX = 4096 / BM;          // x-tiles per z
  const int nb = gridDim.x, per = nb >> 3, bid = blockIdx.x;
  const int swz = (bid & 7) * per + (bid >> 3);
  const int z = swz / (NX * 8);
  const int rem = swz % (NX * 8);
  const int m0 = (rem >> 3) * BM, n0 = (rem & 7) * 128;

  const void* Av = z == 0 ? A0v : (z == 1 ? A1v : A2v);
  const unsigned short* Bw = z == 0 ? W0 : (z == 1 ? W1 : W2);
  const float* bias = z == 0 ? b0 : (z == 1 ? b1 : b2);
  OT* C = z == 0 ? C0 : (z == 1 ? C1 : C2);
  const float scale = z == 0 ? s0 : (z == 1 ? s1 : s2);

  __shared__ alignas(16) unsigned short As[2][BM * 64];    // [row][64] swizzled
  __shared__ alignas(16) unsigned short Bs[2][128 * 64];   // [row][64] swizzled
  const int tid = threadIdx.x;
  const int wid = tid >> 6;
  const int lane = tid & 63;
  const int lo = lane & 15, hi = lane >> 4;
  const int wr = wid >> 1, wc = wid & 1;
  f32x4 acc[MF][4] = {};

  float4 fa[MF][2];   // A reg-staging (AF32 only)

  auto loadA = [&](int k0) {
    if constexpr (AF32) {
#pragma unroll
      for (int j = 0; j < MF; ++j) {
        const int chunk = j * 256 + tid;
        const int row = chunk >> 3, cl = (chunk & 7) ^ (row & 7);
        const float* p = (const float*)Av + (size_t)(m0 + row) * DMOD + k0 + cl * 8;
        fa[j][0] = *(const float4*)p;
        fa[j][1] = *(const float4*)(p + 4);
      }
    }
  };
  auto writeA = [&](int buf) {
    if constexpr (AF32) {
#pragma unroll
      for (int j = 0; j < MF; ++j) {
        const int chunk = j * 256 + tid;
        u32x4 o;
        o[0] = cvt_pk_bf16(fa[j][0].x, fa[j][0].y);
        o[1] = cvt_pk_bf16(fa[j][0].z, fa[j][0].w);
        o[2] = cvt_pk_bf16(fa[j][1].x, fa[j][1].y);
        o[3] = cvt_pk_bf16(fa[j][1].z, fa[j][1].w);
        *(u32x4*)((char*)As + buf * (BM * 128) + chunk * 16) = o;
      }
    }
  };
  auto stage = [&](int buf, int k0) {
    if constexpr (!AF32) {
#pragma unroll
      for (int i = 0; i < MF; ++i) {
        const int chunk = i * 256 + tid;
        const int row = chunk >> 3, cl = (chunk & 7) ^ (row & 7);
        gload_lds16((const unsigned short*)Av + (size_t)(m0 + row) * DMOD + k0 + cl * 8,
                    (const char*)As + buf * (BM * 128) + chunk * 16);
      }
    }
#pragma unroll
    for (int i = 0; i < 4; ++i) {
      const int chunk = i * 256 + tid;
      const int row = chunk >> 3, cl = (chunk & 7) ^ (row & 7);
      gload_lds16(Bw + (size_t)(n0 + row) * DMOD + k0 + cl * 8,
                  (const char*)Bs + buf * 16384 + chunk * 16);
    }
  };

  loadA(0);
  writeA(0);
  stage(0, 0);

  if constexpr (MEXP) {
    // mask int32 -> fragment-ordered byte masks, ~11 words/thread.
    // mx word W = ((b*T+q)*16 + kt)*32 + hi*8 + ct; byte r covers
    // k = kt*128 + ct*16 + hi*4 + r (0xFF keep / 0x00 masked).
    const int g = bid * 256 + tid;                 // 0..196607
#pragma unroll
    for (int j = 0; j < 11; ++j) {
      const size_t W = (size_t)g + (size_t)j * 196608;
      if (W < (size_t)NBATCH * TSEQ * 512) {
        const int h2 = (int)((W >> 3) & 3), c2 = (int)(W & 7);
        const size_t bqkt = W >> 5;
        const int k2 = (int)(bqkt & 15);
        const size_t bq = bqkt >> 4;
        const int4 mm = *(const int4*)(mmask + bq * TSEQ + k2 * 128 + c2 * 16 + h2 * 4);
        const uint32_t o = (mm.x ? 0xFFu : 0u) | (mm.y ? 0xFF00u : 0u) |
                           (mm.z ? 0xFF0000u : 0u) | (mm.w ? 0xFF000000u : 0u);
        mxout[W] = o;
      }
    }
  }

  __syncthreads();    // K-step 0 landed

  for (int k0 = 0; k0 < DMOD; k0 += 64) {
    const int cur = (k0 >> 6) & 1;
    const bool more = k0 + 64 < DMOD;
    if (more) { loadA(k0 + 64); stage(cur ^ 1, k0 + 64); }

#pragma unroll
    for (int kk = 0; kk < 2; ++kk) {
      bf16x8 af[MF], bfr[4];
#pragma unroll
      for (int m = 0; m < MF; ++m) {
        const int row = wr * (MF * 16) + m * 16 + lo;
        af[m] = *(const bf16x8*)((const char*)As + cur * (BM * 128) +
                                 row * 128 + (((kk * 4 + hi) ^ (lo & 7)) * 16));
      }
#pragma unroll
      for (int n = 0; n < 4; ++n) {
        const int row = wc * 64 + n * 16 + lo;
        bfr[n] = *(const bf16x8*)((const char*)Bs + cur * 16384 +
                                  row * 128 + (((kk * 4 + hi) ^ (lo & 7)) * 16));
      }
#pragma unroll
      for (int m = 0; m < MF; ++m)
#pragma unroll
        for (int n = 0; n < 4; ++n)
          acc[m][n] = __builtin_amdgcn_mfma_f32_16x16x32_bf16(af[m], bfr[n], acc[m][n], 0, 0, 0);
    }

    if (more) writeA(cur ^ 1);
    __syncthreads();
  }

#pragma unroll
  for (int n = 0; n < 4; ++n) {
    const int col = n0 + wc * 64 + n * 16 + lo;
    const float bv = bias[col];
#pragma unroll
    for (int m = 0; m < MF; ++m) {
      const int row = m0 + wr * (MF * 16) + m * 16 + hi * 4;
#pragma unroll
      for (int r = 0; r < 4; ++r)
        store_c(C, (size_t)(row + r) * DMOD + col, (acc[m][n][r] + bv) * scale);
    }
  }
}

// ---------------- V transpose + nu-permute: Vp[B*T][D] -> Vt'[...][nu(t)] ---
__global__ __launch_bounds__(256) void transpose_v(const unsigned short* __restrict__ Vp,
                                                   unsigned short* __restrict__ Vt) {
  __shared__ alignas(16) unsigned short tile[64][72];
  const int tid = threadIdx.x;
  const int bt0 = blockIdx.x * 64;
  const int h = blockIdx.y;
  const int b = bt0 >> 11;
  const int t0 = bt0 & (TSEQ - 1);
#pragma unroll
  for (int i = 0; i < 2; ++i) {
    const int chunk = i * 256 + tid;
    const int row = chunk >> 3, c = chunk & 7;
    *(uint4*)((char*)&tile[row][0] + c * 16) =
        *(const uint4*)(Vp + (size_t)(bt0 + row) * DMOD + h * 64 + c * 8);
  }
  __syncthreads();
#pragma unroll
  for (int i = 0; i < 2; ++i) {
    const int chunk = i * 256 + tid;
    const int dk = chunk >> 3, c = chunk & 7;
    u16x8 o;
#pragma unroll
    for (int j = 0; j < 8; ++j) {
      const int x = c * 8 + j;   // nu index within the 64-tile
      const int kl = (x & 32) | ((x & 24) >> 1) | ((x & 4) << 2) | (x & 3);
      o[j] = tile[kl][dk];
    }
    *(u16x8*)(Vt + ((size_t)(b * NHEAD + h) * 64 + dk) * TSEQ + t0 + c * 8) = o;
  }
}

// ---------------- flash attention: exp2-direct, byte-mask AND --------------
// (round-15 configuration — frozen best)
__global__ __launch_bounds__(512, 4) void attn_kernel(const unsigned short* __restrict__ Qp,
                                                      const unsigned short* __restrict__ Kp,
                                                      const unsigned short* __restrict__ Vt,
                                                      const uint32_t* __restrict__ mx,
                                                      unsigned short* __restrict__ AO) {
  __shared__ alignas(16) unsigned short Ks[2][128 * 64];   // [kcol][d] chunk-XOR swizzled
  __shared__ alignas(16) unsigned short Vs[2][64 * 128];   // [dk][nu]  chunk-XOR swizzled
  const int tid = threadIdx.x;
  const int w = tid >> 6, lane = tid & 63;
  const int lo = lane & 15, hi = lane >> 4;
  const int f = blockIdx.x;                 // 0..511, XCD swizzle
  const int swz = (f & 7) * 64 + (f >> 3);
  const int q0 = (swz & 15) * 128;
  const int h = (swz >> 4) & 15;
  const int b = swz >> 8;

  bf16x8 qf[2];
  {
    const unsigned short* qsrc =
        Qp + (size_t)(b * TSEQ + q0 + w * 16 + lo) * DMOD + h * 64 + hi * 8;
    qf[0] = *(const bf16x8*)qsrc;
    qf[1] = *(const bf16x8*)(qsrc + 32);
  }

  bf16x8 ones;
  {
    u32x4 od;
    od[0] = 0x3F803F80u; od[1] = 0x3F803F80u; od[2] = 0x3F803F80u; od[3] = 0x3F803F80u;
    ones = __builtin_bit_cast(bf16x8, od);
  }

  f32x4 o_acc[4] = {};
  f32x4 l_acc = {};

  const size_t kbase = (size_t)(b * TSEQ) * DMOD + h * 64;
  const size_t vbase = (size_t)(b * NHEAD + h) * 64 * TSEQ;

  const int c0 = tid, c1 = 512 + tid;
  const unsigned short* kp0 = Kp + kbase + (size_t)(c0 >> 3) * DMOD + ((c0 & 7) ^ ((c0 >> 3) & 7)) * 8;
  const unsigned short* kp1 = Kp + kbase + (size_t)(c1 >> 3) * DMOD + ((c1 & 7) ^ ((c1 >> 3) & 7)) * 8;
  const unsigned short* vp0 = Vt + vbase + (size_t)(c0 >> 4) * TSEQ + ((c0 & 15) ^ ((c0 >> 4) & 7)) * 8;
  const unsigned short* vp1 = Vt + vbase + (size_t)(c1 >> 4) * TSEQ + ((c1 & 15) ^ ((c1 >> 4) & 7)) * 8;
  const uint32_t* mp = mx + (size_t)(b * TSEQ + q0 + w * 16 + lo) * 512 + hi * 8;
  const int wb0 = c0 * 16, wb1 = c1 * 16;

  int koffA[8], koffB[8];
#pragma unroll
  for (int ct = 0; ct < 8; ++ct) {
    const int kcol = ct * 16 + lo;
    koffA[ct] = kcol * 128 + ((hi ^ (kcol & 7)) * 16);
    koffB[ct] = kcol * 128 + (((4 + hi) ^ (kcol & 7)) * 16);
  }
  int voff[4][4];
#pragma unroll
  for (int vt = 0; vt < 4; ++vt) {
    const int dk = vt * 16 + lo;
#pragma unroll
    for (int c = 0; c < 4; ++c) voff[vt][c] = dk * 256 + (((c * 4 + hi) ^ (dk & 7)) * 16);
  }

  auto stage = [&](int buf) {
    gload_lds16(kp0, (const char*)Ks[buf] + wb0);
    gload_lds16(kp1, (const char*)Ks[buf] + wb1);
    gload_lds16(vp0, (const char*)Vs[buf] + wb0);
    gload_lds16(vp1, (const char*)Vs[buf] + wb1);
    kp0 += (size_t)128 * DMOD; kp1 += (size_t)128 * DMOD;
    vp0 += 128; vp1 += 128;
  };

  const uint32_t selA = 0x01010000u, selB = 0x03030202u;
  const int NT = TSEQ / 128;   // 16

  uint4 mc0 = *(const uint4*)mp, mc1 = *(const uint4*)(mp + 4);
  mp += 32;
  stage(0);
  __syncthreads();   // tile 0 landed

  for (int kt = 0; kt < NT; ++kt) {
    uint4 mn0 = mc0, mn1 = mc1;
    if (kt + 1 < NT) {
      mn0 = *(const uint4*)mp;
      mn1 = *(const uint4*)(mp + 4);
      mp += 32;
      stage((kt + 1) & 1);
    }

    // S^T = mfma(K, Q): lane holds S[q=lo][k=ct*16+hi*4+r]
    const char* ksb = (const char*)Ks[kt & 1];
    const char* vsb = (const char*)Vs[kt & 1];
    f32x4 s[8];
    __builtin_amdgcn_s_setprio(1);
#pragma unroll
    for (int ct = 0; ct < 8; ++ct) {
      bf16x8 kf0 = *(const bf16x8*)(ksb + koffA[ct]);
      bf16x8 kf1 = *(const bf16x8*)(ksb + koffB[ct]);
      f32x4 zz = {0.f, 0.f, 0.f, 0.f};
      s[ct] = __builtin_amdgcn_mfma_f32_16x16x32_bf16(kf0, qf[0], zz, 0, 0, 0);
      s[ct] = __builtin_amdgcn_mfma_f32_16x16x32_bf16(kf1, qf[1], s[ct], 0, 0, 0);
    }
    __builtin_amdgcn_s_setprio(0);

    // p = 2^s (masked -> 2^-1e9 = 0 via byte-mask AND below)
#pragma unroll
    for (int ct = 0; ct < 8; ++ct) {
      s[ct][0] = __builtin_exp2f(s[ct][0]);
      s[ct][1] = __builtin_exp2f(s[ct][1]);
      s[ct][2] = __builtin_exp2f(s[ct][2]);
      s[ct][3] = __builtin_exp2f(s[ct][3]);
    }

    bf16x8 pf[4];
#pragma unroll
    for (int c = 0; c < 4; ++c) {
      const uint32_t We = c == 0 ? mc0.x : (c == 1 ? mc0.z : (c == 2 ? mc1.x : mc1.z));
      const uint32_t Wo = c == 0 ? mc0.y : (c == 1 ? mc0.w : (c == 2 ? mc1.y : mc1.w));
      u32x4 pd;
      pd[0] = cvt_pk_bf16(s[2 * c][0], s[2 * c][1]) & __builtin_amdgcn_perm(We, We, selA);
      pd[1] = cvt_pk_bf16(s[2 * c][2], s[2 * c][3]) & __builtin_amdgcn_perm(We, We, selB);
      pd[2] = cvt_pk_bf16(s[2 * c + 1][0], s[2 * c + 1][1]) & __builtin_amdgcn_perm(Wo, Wo, selA);
      pd[3] = cvt_pk_bf16(s[2 * c + 1][2], s[2 * c + 1][3]) & __builtin_amdgcn_perm(Wo, Wo, selB);
      pf[c] = __builtin_bit_cast(bf16x8, pd);
    }

    __builtin_amdgcn_s_setprio(1);
#pragma unroll
    for (int vt = 0; vt < 4; ++vt) {
#pragma unroll
      for (int c = 0; c < 4; ++c) {
        bf16x8 vf = *(const bf16x8*)(vsb + voff[vt][c]);
        o_acc[vt] = __builtin_amdgcn_mfma_f32_16x16x32_bf16(pf[c], vf, o_acc[vt], 0, 0, 0);
      }
    }
#pragma unroll
    for (int c = 0; c < 4; ++c)
      l_acc = __builtin_amdgcn_mfma_f32_16x16x32_bf16(pf[c], ones, l_acc, 0, 0, 0);
    __builtin_amdgcn_s_setprio(0);

    __syncthreads();
    mc0 = mn0; mc1 = mn1;
  }

#pragma unroll
  for (int r = 0; r < 4; ++r) {
    const float rl = 1.0f / l_acc[r];
    const size_t orow = (size_t)(b * TSEQ + q0 + w * 16 + hi * 4 + r) * DMOD + h * 64;
#pragma unroll
    for (int vt = 0; vt < 4; ++vt)
      AO[orow + vt * 16 + lo] = f2bf(o_acc[vt][r] * rl);
  }
}

// ---------------- launcher -------------------------------------------------
extern "C" void kernel_launch(void* const* d_in, const int* in_sizes, int n_in,
                              void* d_out, int out_size, void* d_ws, size_t ws_size,
                              hipStream_t stream) {
  const float* q  = (const float*)d_in[0];
  const float* k  = (const float*)d_in[1];
  const float* v  = (const float*)d_in[2];
  const int* mask = (const int*)d_in[3];
  const float* Wq = (const float*)d_in[4];
  const float* bq = (const float*)d_in[5];
  const float* Wk = (const float*)d_in[6];
  const float* bk = (const float*)d_in[7];
  const float* Wv = (const float*)d_in[8];
  const float* bv = (const float*)d_in[9];
  const float* Wo = (const float*)d_in[10];
  const float* bo = (const float*)d_in[11];
  float* out = (float*)d_out;

  char* ws = (char*)d_ws;
  const size_t SZ_BT = (size_t)MT * DMOD * 2;   // 8 MiB

  unsigned short* Qp  = (unsigned short*)(ws + 0);
  unsigned short* Kp  = (unsigned short*)(ws + SZ_BT);
  unsigned short* Vp  = (unsigned short*)(ws + 2 * SZ_BT);
  unsigned short* Vt  = (unsigned short*)(ws + 3 * SZ_BT);
  unsigned short* Wqb = (unsigned short*)(ws + 4 * SZ_BT);          // 4 weights, 8 MiB
  uint32_t*       mx  = (uint32_t*)(ws + 5 * SZ_BT);                // 8.39 MiB
  unsigned short* AO  = Vp;   // Vp dead after transpose_v
  unsigned short* Wob = Wqb + 3 * DMOD * DMOD;

  const int nW = DMOD * DMOD;

  // weights fp32 -> bf16 (mask expansion now rides inside the QKV GEMM)
  cvt_w<<<dim3(4096), 256, 0, stream>>>(Wq, Wk, Wv, Wo, Wqb);

  const float qs = 0.125f * LOG2E;
  // QKV projections + mask expand: fp32 A direct, BK=64, grid 768
  gemm_bt<unsigned short, 4, true, true><<<dim3(768), 256, 0, stream>>>(
      q, k, v, Wqb, Wqb + nW, Wqb + 2 * nW, bq, bk, bv, Qp, Kp, Vp, qs, 1.0f, 1.0f,
      mask, mx);

  transpose_v<<<dim3(MT / 64, NHEAD), 256, 0, stream>>>(Vp, Vt);

  attn_kernel<<<dim3(512), 512, 0, stream>>>(Qp, Kp, Vt, mx, AO);

  gemm_bt<float, 2, false, false><<<dim3(512), 256, 0, stream>>>(
      AO, AO, AO, Wob, Wob, Wob, bo, bo, bo, out, out, out, 1.0f, 1.0f, 1.0f,
      nullptr, nullptr);
}

// Round 18
// 138.714 us; speedup vs baseline: 1.3986x; 1.0250x over previous
//
#include <hip/hip_runtime.h>
#include <cstdint>
#include <cstddef>

#define TSEQ 2048
#define DMOD 1024
#define NHEAD 16
#define NBATCH 2
#define MT (NBATCH * TSEQ)
#define LOG2E 1.44269504088896340736f

typedef __attribute__((ext_vector_type(8))) __bf16 bf16x8;
typedef __attribute__((ext_vector_type(4))) float f32x4;
typedef __attribute__((ext_vector_type(8))) unsigned short u16x8;
typedef __attribute__((ext_vector_type(4))) unsigned short u16x4;
typedef __attribute__((ext_vector_type(4))) uint32_t u32x4;

__device__ __forceinline__ unsigned short f2bf(float f) {
  uint32_t u = __builtin_bit_cast(uint32_t, f);
  u += 0x7fffu + ((u >> 16) & 1u);   // RNE (inputs finite)
  return (unsigned short)(u >> 16);
}

__device__ __forceinline__ uint32_t cvt_pk_bf16(float a, float b) {
  uint32_t r;
  asm("v_cvt_pk_bf16_f32 %0, %1, %2" : "=v"(r) : "v"(a), "v"(b));
  return r;
}

__device__ __forceinline__ void gload_lds16(const void* g, const void* l) {
  auto gp = (const __attribute__((address_space(1))) uint32_t*)((uintptr_t)g);
  auto lp = (__attribute__((address_space(3))) uint32_t*)((uintptr_t)l);
  __builtin_amdgcn_global_load_lds(gp, lp, 16, 0, 0);
}

// ------- merged: weight fp32->bf16 cvt (blocks 0..4095) + mask expand ------
// mask part: mx u32 index W = ((b*T+q)*16 + kt)*32 + hi*8 + ct; byte r of W
// covers k = kt*128 + ct*16 + hi*4 + r (0xFF keep / 0x00 masked).
__global__ __launch_bounds__(256) void cvt_wm(const float* __restrict__ w0,
                                              const float* __restrict__ w1,
                                              const float* __restrict__ w2,
                                              const float* __restrict__ w3,
                                              const int* __restrict__ m,
                                              unsigned short* __restrict__ dw,
                                              uint32_t* __restrict__ mx) {
  const int bx = blockIdx.x;
  if (bx < 4096) {
    const size_t idx = ((size_t)bx * 256 + threadIdx.x) * 4;   // 4 weights x 1M elems
    const int wsel = (int)(idx >> 20);
    const float* s = wsel == 0 ? w0 : (wsel == 1 ? w1 : (wsel == 2 ? w2 : w3));
    const float4 t = *(const float4*)(s + (idx & 0xFFFFFu));
    u16x4 o;
    o[0] = f2bf(t.x); o[1] = f2bf(t.y); o[2] = f2bf(t.z); o[3] = f2bf(t.w);
    *(u16x4*)(dw + idx) = o;
  } else {
    const size_t W = (size_t)(bx - 4096) * 256 + threadIdx.x;  // < 2*T*16*32
    const int hi = (int)((W >> 3) & 3), ct = (int)(W & 7);
    const size_t bqkt = W >> 5;
    const int kt = (int)(bqkt & 15);
    const size_t bq = bqkt >> 4;
    const int4 mm = *(const int4*)(m + bq * TSEQ + kt * 128 + ct * 16 + hi * 4);
    const uint32_t o = (mm.x ? 0xFFu : 0u) | (mm.y ? 0xFF00u : 0u) |
                       (mm.z ? 0xFF0000u : 0u) | (mm.w ? 0xFF000000u : 0u);
    mx[W] = o;
  }
}

// ---------------- GEMM: C = A[M x 1024] * W[1024x1024]^T + bias, *scale ----
// BK=64: 32 MFMA per barrier interval (16 barriers for K=1024), XOR-swizzled
// LDS (bank-conflict-free, verified 0 in PMC). AF32: A fp32 direct from
// inputs, reg-staged with fused cvt_pk (issue-early / write-late).
__device__ __forceinline__ void store_c(unsigned short* C, size_t idx, float v) { C[idx] = f2bf(v); }
__device__ __forceinline__ void store_c(float* C, size_t idx, float v) { C[idx] = v; }

template <typename OT, int MF, bool AF32>
__global__ __launch_bounds__(256) void gemm_bt(const void* __restrict__ A0v,
                                               const void* __restrict__ A1v,
                                               const void* __restrict__ A2v,
                                               const unsigned short* __restrict__ W0,
                                               const unsigned short* __restrict__ W1,
                                               const unsigned short* __restrict__ W2,
                                               const float* __restrict__ b0,
                                               const float* __restrict__ b1,
                                               const float* __restrict__ b2,
                                               OT* __restrict__ C0, OT* __restrict__ C1, OT* __restrict__ C2,
                                               float s0, float s1, float s2) {
  constexpr int BM = MF * 32;
  constexpr int NX = 4096 / BM;          // x-tiles per z
  const int nb = gridDim.x, per = nb >> 3, bid = blockIdx.x;
  const int swz = (bid & 7) * per + (bid >> 3);
  const int z = swz / (NX * 8);
  const int rem = swz % (NX * 8);
  const int m0 = (rem >> 3) * BM, n0 = (rem & 7) * 128;

  const void* Av = z == 0 ? A0v : (z == 1 ? A1v : A2v);
  const unsigned short* Bw = z == 0 ? W0 : (z == 1 ? W1 : W2);
  const float* bias = z == 0 ? b0 : (z == 1 ? b1 : b2);
  OT* C = z == 0 ? C0 : (z == 1 ? C1 : C2);
  const float scale = z == 0 ? s0 : (z == 1 ? s1 : s2);

  __shared__ alignas(16) unsigned short As[2][BM * 64];    // [row][64] swizzled
  __shared__ alignas(16) unsigned short Bs[2][128 * 64];   // [row][64] swizzled
  const int tid = threadIdx.x;
  const int wid = tid >> 6;
  const int lane = tid & 63;
  const int lo = lane & 15, hi = lane >> 4;
  const int wr = wid >> 1, wc = wid & 1;
  f32x4 acc[MF][4] = {};

  float4 fa[MF][2];   // A reg-staging (AF32 only); MF chunks x 32 B

  auto loadA = [&](int k0) {
    if constexpr (AF32) {
#pragma unroll
      for (int j = 0; j < MF; ++j) {
        const int chunk = j * 256 + tid;
        const int row = chunk >> 3, cl = (chunk & 7) ^ (row & 7);
        const float* p = (const float*)Av + (size_t)(m0 + row) * DMOD + k0 + cl * 8;
        fa[j][0] = *(const float4*)p;
        fa[j][1] = *(const float4*)(p + 4);
      }
    }
  };
  auto writeA = [&](int buf) {
    if constexpr (AF32) {
#pragma unroll
      for (int j = 0; j < MF; ++j) {
        const int chunk = j * 256 + tid;
        u32x4 o;
        o[0] = cvt_pk_bf16(fa[j][0].x, fa[j][0].y);
        o[1] = cvt_pk_bf16(fa[j][0].z, fa[j][0].w);
        o[2] = cvt_pk_bf16(fa[j][1].x, fa[j][1].y);
        o[3] = cvt_pk_bf16(fa[j][1].z, fa[j][1].w);
        *(u32x4*)((char*)As + buf * (BM * 128) + chunk * 16) = o;
      }
    }
  };
  auto stage = [&](int buf, int k0) {
    if constexpr (!AF32) {
#pragma unroll
      for (int i = 0; i < MF; ++i) {     // BM*8/256 = MF chunks per thread
        const int chunk = i * 256 + tid;
        const int row = chunk >> 3, cl = (chunk & 7) ^ (row & 7);
        gload_lds16((const unsigned short*)Av + (size_t)(m0 + row) * DMOD + k0 + cl * 8,
                    (const char*)As + buf * (BM * 128) + chunk * 16);
      }
    }
#pragma unroll
    for (int i = 0; i < 4; ++i) {        // 128*8/256 = 4 chunks per thread
      const int chunk = i * 256 + tid;
      const int row = chunk >> 3, cl = (chunk & 7) ^ (row & 7);
      gload_lds16(Bw + (size_t)(n0 + row) * DMOD + k0 + cl * 8,
                  (const char*)Bs + buf * 16384 + chunk * 16);
    }
  };

  loadA(0);
  writeA(0);          // reg-dep waits the fp32 loads; ds_write to buf0
  stage(0, 0);        // B (and bf16-A) global_load_lds
  __syncthreads();    // K-step 0 landed

  for (int k0 = 0; k0 < DMOD; k0 += 64) {
    const int cur = (k0 >> 6) & 1;
    const bool more = k0 + 64 < DMOD;
    if (more) { loadA(k0 + 64); stage(cur ^ 1, k0 + 64); }

#pragma unroll
    for (int kk = 0; kk < 2; ++kk) {
      bf16x8 af[MF], bfr[4];
#pragma unroll
      for (int m = 0; m < MF; ++m) {
        const int row = wr * (MF * 16) + m * 16 + lo;
        af[m] = *(const bf16x8*)((const char*)As + cur * (BM * 128) +
                                 row * 128 + (((kk * 4 + hi) ^ (lo & 7)) * 16));
      }
#pragma unroll
      for (int n = 0; n < 4; ++n) {
        const int row = wc * 64 + n * 16 + lo;
        bfr[n] = *(const bf16x8*)((const char*)Bs + cur * 16384 +
                                  row * 128 + (((kk * 4 + hi) ^ (lo & 7)) * 16));
      }
#pragma unroll
      for (int m = 0; m < MF; ++m)
#pragma unroll
        for (int n = 0; n < 4; ++n)
          acc[m][n] = __builtin_amdgcn_mfma_f32_16x16x32_bf16(af[m], bfr[n], acc[m][n], 0, 0, 0);
    }

    if (more) writeA(cur ^ 1);   // cvt+ds_write into next buf (post-compute)
    __syncthreads();             // next-step stage landed; cur fully read
  }

#pragma unroll
  for (int n = 0; n < 4; ++n) {
    const int col = n0 + wc * 64 + n * 16 + lo;
    const float bv = bias[col];
#pragma unroll
    for (int m = 0; m < MF; ++m) {
      const int row = m0 + wr * (MF * 16) + m * 16 + hi * 4;
#pragma unroll
      for (int r = 0; r < 4; ++r)
        store_c(C, (size_t)(row + r) * DMOD + col, (acc[m][n][r] + bv) * scale);
    }
  }
}

// ---------------- V transpose + nu-permute: Vp[B*T][D] -> Vt'[...][nu(t)] ---
__global__ __launch_bounds__(256) void transpose_v(const unsigned short* __restrict__ Vp,
                                                   unsigned short* __restrict__ Vt) {
  __shared__ alignas(16) unsigned short tile[64][72];
  const int tid = threadIdx.x;
  const int bt0 = blockIdx.x * 64;
  const int h = blockIdx.y;
  const int b = bt0 >> 11;
  const int t0 = bt0 & (TSEQ - 1);
#pragma unroll
  for (int i = 0; i < 2; ++i) {
    const int chunk = i * 256 + tid;
    const int row = chunk >> 3, c = chunk & 7;
    *(uint4*)((char*)&tile[row][0] + c * 16) =
        *(const uint4*)(Vp + (size_t)(bt0 + row) * DMOD + h * 64 + c * 8);
  }
  __syncthreads();
#pragma unroll
  for (int i = 0; i < 2; ++i) {
    const int chunk = i * 256 + tid;
    const int dk = chunk >> 3, c = chunk & 7;
    u16x8 o;
#pragma unroll
    for (int j = 0; j < 8; ++j) {
      const int x = c * 8 + j;   // nu index within the 64-tile
      const int kl = (x & 32) | ((x & 24) >> 1) | ((x & 4) << 2) | (x & 3);
      o[j] = tile[kl][dk];
    }
    *(u16x8*)(Vt + ((size_t)(b * NHEAD + h) * 64 + dk) * TSEQ + t0 + c * 8) = o;
  }
}

// ---------------- flash attention: exp2-direct, byte-mask AND --------------
// (round-8 configuration — frozen best: 512 thr, 16 q/wave, KVBLK=128)
__global__ __launch_bounds__(512, 4) void attn_kernel(const unsigned short* __restrict__ Qp,
                                                      const unsigned short* __restrict__ Kp,
                                                      const unsigned short* __restrict__ Vt,
                                                      const uint32_t* __restrict__ mx,
                                                      unsigned short* __restrict__ AO) {
  __shared__ alignas(16) unsigned short Ks[2][128 * 64];   // [kcol][d] chunk-XOR swizzled
  __shared__ alignas(16) unsigned short Vs[2][64 * 128];   // [dk][nu]  chunk-XOR swizzled
  const int tid = threadIdx.x;
  const int w = tid >> 6, lane = tid & 63;
  const int lo = lane & 15, hi = lane >> 4;
  const int f = blockIdx.x;                 // 0..511, XCD swizzle
  const int swz = (f & 7) * 64 + (f >> 3);
  const int q0 = (swz & 15) * 128;
  const int h = (swz >> 4) & 15;
  const int b = swz >> 8;

  bf16x8 qf[2];
  {
    const unsigned short* qsrc =
        Qp + (size_t)(b * TSEQ + q0 + w * 16 + lo) * DMOD + h * 64 + hi * 8;
    qf[0] = *(const bf16x8*)qsrc;
    qf[1] = *(const bf16x8*)(qsrc + 32);
  }

  bf16x8 ones;
  {
    u32x4 od;
    od[0] = 0x3F803F80u; od[1] = 0x3F803F80u; od[2] = 0x3F803F80u; od[3] = 0x3F803F80u;
    ones = __builtin_bit_cast(bf16x8, od);
  }

  f32x4 o_acc[4] = {};
  f32x4 l_acc = {};

  const size_t kbase = (size_t)(b * TSEQ) * DMOD + h * 64;
  const size_t vbase = (size_t)(b * NHEAD + h) * 64 * TSEQ;

  const int c0 = tid, c1 = 512 + tid;
  const unsigned short* kp0 = Kp + kbase + (size_t)(c0 >> 3) * DMOD + ((c0 & 7) ^ ((c0 >> 3) & 7)) * 8;
  const unsigned short* kp1 = Kp + kbase + (size_t)(c1 >> 3) * DMOD + ((c1 & 7) ^ ((c1 >> 3) & 7)) * 8;
  const unsigned short* vp0 = Vt + vbase + (size_t)(c0 >> 4) * TSEQ + ((c0 & 15) ^ ((c0 >> 4) & 7)) * 8;
  const unsigned short* vp1 = Vt + vbase + (size_t)(c1 >> 4) * TSEQ + ((c1 & 15) ^ ((c1 >> 4) & 7)) * 8;
  const uint32_t* mp = mx + (size_t)(b * TSEQ + q0 + w * 16 + lo) * 512 + hi * 8;
  const int wb0 = c0 * 16, wb1 = c1 * 16;

  int koffA[8], koffB[8];
#pragma unroll
  for (int ct = 0; ct < 8; ++ct) {
    const int kcol = ct * 16 + lo;
    koffA[ct] = kcol * 128 + ((hi ^ (kcol & 7)) * 16);
    koffB[ct] = kcol * 128 + (((4 + hi) ^ (kcol & 7)) * 16);
  }
  int voff[4][4];
#pragma unroll
  for (int vt = 0; vt < 4; ++vt) {
    const int dk = vt * 16 + lo;
#pragma unroll
    for (int c = 0; c < 4; ++c) voff[vt][c] = dk * 256 + (((c * 4 + hi) ^ (dk & 7)) * 16);
  }

  auto stage = [&](int buf) {
    gload_lds16(kp0, (const char*)Ks[buf] + wb0);
    gload_lds16(kp1, (const char*)Ks[buf] + wb1);
    gload_lds16(vp0, (const char*)Vs[buf] + wb0);
    gload_lds16(vp1, (const char*)Vs[buf] + wb1);
    kp0 += (size_t)128 * DMOD; kp1 += (size_t)128 * DMOD;
    vp0 += 128; vp1 += 128;
  };

  const uint32_t selA = 0x01010000u, selB = 0x03030202u;
  const int NT = TSEQ / 128;   // 16

  uint4 mc0 = *(const uint4*)mp, mc1 = *(const uint4*)(mp + 4);
  mp += 32;
  stage(0);
  __syncthreads();   // tile 0 landed

  for (int kt = 0; kt < NT; ++kt) {
    uint4 mn0 = mc0, mn1 = mc1;
    if (kt + 1 < NT) {
      mn0 = *(const uint4*)mp;
      mn1 = *(const uint4*)(mp + 4);
      mp += 32;
      stage((kt + 1) & 1);
    }

    // S^T = mfma(K, Q): lane holds S[q=lo][k=ct*16+hi*4+r]
    const char* ksb = (const char*)Ks[kt & 1];
    const char* vsb = (const char*)Vs[kt & 1];
    f32x4 s[8];
    __builtin_amdgcn_s_setprio(1);
#pragma unroll
    for (int ct = 0; ct < 8; ++ct) {
      bf16x8 kf0 = *(const bf16x8*)(ksb + koffA[ct]);
      bf16x8 kf1 = *(const bf16x8*)(ksb + koffB[ct]);
      f32x4 zz = {0.f, 0.f, 0.f, 0.f};
      s[ct] = __builtin_amdgcn_mfma_f32_16x16x32_bf16(kf0, qf[0], zz, 0, 0, 0);
      s[ct] = __builtin_amdgcn_mfma_f32_16x16x32_bf16(kf1, qf[1], s[ct], 0, 0, 0);
    }
    __builtin_amdgcn_s_setprio(0);

    // p = 2^s (masked -> 2^-1e9 = 0 via byte-mask AND below)
#pragma unroll
    for (int ct = 0; ct < 8; ++ct) {
      s[ct][0] = __builtin_exp2f(s[ct][0]);
      s[ct][1] = __builtin_exp2f(s[ct][1]);
      s[ct][2] = __builtin_exp2f(s[ct][2]);
      s[ct][3] = __builtin_exp2f(s[ct][3]);
    }

    bf16x8 pf[4];
#pragma unroll
    for (int c = 0; c < 4; ++c) {
      const uint32_t We = c == 0 ? mc0.x : (c == 1 ? mc0.z : (c == 2 ? mc1.x : mc1.z));
      const uint32_t Wo = c == 0 ? mc0.y : (c == 1 ? mc0.w : (c == 2 ? mc1.y : mc1.w));
      u32x4 pd;
      pd[0] = cvt_pk_bf16(s[2 * c][0], s[2 * c][1]) & __builtin_amdgcn_perm(We, We, selA);
      pd[1] = cvt_pk_bf16(s[2 * c][2], s[2 * c][3]) & __builtin_amdgcn_perm(We, We, selB);
      pd[2] = cvt_pk_bf16(s[2 * c + 1][0], s[2 * c + 1][1]) & __builtin_amdgcn_perm(Wo, Wo, selA);
      pd[3] = cvt_pk_bf16(s[2 * c + 1][2], s[2 * c + 1][3]) & __builtin_amdgcn_perm(Wo, Wo, selB);
      pf[c] = __builtin_bit_cast(bf16x8, pd);
    }

    __builtin_amdgcn_s_setprio(1);
#pragma unroll
    for (int vt = 0; vt < 4; ++vt) {
#pragma unroll
      for (int c = 0; c < 4; ++c) {
        bf16x8 vf = *(const bf16x8*)(vsb + voff[vt][c]);
        o_acc[vt] = __builtin_amdgcn_mfma_f32_16x16x32_bf16(pf[c], vf, o_acc[vt], 0, 0, 0);
      }
    }
#pragma unroll
    for (int c = 0; c < 4; ++c)
      l_acc = __builtin_amdgcn_mfma_f32_16x16x32_bf16(pf[c], ones, l_acc, 0, 0, 0);
    __builtin_amdgcn_s_setprio(0);

    __syncthreads();
    mc0 = mn0; mc1 = mn1;
  }

#pragma unroll
  for (int r = 0; r < 4; ++r) {
    const float rl = 1.0f / l_acc[r];
    const size_t orow = (size_t)(b * TSEQ + q0 + w * 16 + hi * 4 + r) * DMOD + h * 64;
#pragma unroll
    for (int vt = 0; vt < 4; ++vt)
      AO[orow + vt * 16 + lo] = f2bf(o_acc[vt][r] * rl);
  }
}

// ---------------- launcher -------------------------------------------------
extern "C" void kernel_launch(void* const* d_in, const int* in_sizes, int n_in,
                              void* d_out, int out_size, void* d_ws, size_t ws_size,
                              hipStream_t stream) {
  const float* q  = (const float*)d_in[0];
  const float* k  = (const float*)d_in[1];
  const float* v  = (const float*)d_in[2];
  const int* mask = (const int*)d_in[3];
  const float* Wq = (const float*)d_in[4];
  const float* bq = (const float*)d_in[5];
  const float* Wk = (const float*)d_in[6];
  const float* bk = (const float*)d_in[7];
  const float* Wv = (const float*)d_in[8];
  const float* bv = (const float*)d_in[9];
  const float* Wo = (const float*)d_in[10];
  const float* bo = (const float*)d_in[11];
  float* out = (float*)d_out;

  char* ws = (char*)d_ws;
  const size_t SZ_BT = (size_t)MT * DMOD * 2;   // 8 MiB

  unsigned short* Qp  = (unsigned short*)(ws + 0);
  unsigned short* Kp  = (unsigned short*)(ws + SZ_BT);
  unsigned short* Vp  = (unsigned short*)(ws + 2 * SZ_BT);
  unsigned short* Vt  = (unsigned short*)(ws + 3 * SZ_BT);
  unsigned short* Wqb = (unsigned short*)(ws + 4 * SZ_BT);          // 4 weights, 8 MiB
  uint32_t*       mx  = (uint32_t*)(ws + 5 * SZ_BT);                // 8.39 MiB
  unsigned short* AO  = Vp;   // Vp dead after transpose_v
  unsigned short* Wob = Wqb + 3 * DMOD * DMOD;

  const int nW = DMOD * DMOD;

  // weights cvt + mask expand, one launch (both memory-bound streams)
  cvt_wm<<<dim3(4096 + (NBATCH * TSEQ * 16 * 32) / 256), 256, 0, stream>>>(
      Wq, Wk, Wv, Wo, mask, Wqb, mx);

  const float qs = 0.125f * LOG2E;
  // QKV projections: fp32 A read directly from inputs, cvt fused into staging
  gemm_bt<unsigned short, 4, true><<<dim3(768), 256, 0, stream>>>(
      q, k, v, Wqb, Wqb + nW, Wqb + 2 * nW, bq, bk, bv, Qp, Kp, Vp, qs, 1.0f, 1.0f);

  transpose_v<<<dim3(MT / 64, NHEAD), 256, 0, stream>>>(Vp, Vt);

  attn_kernel<<<dim3(512), 512, 0, stream>>>(Qp, Kp, Vt, mx, AO);

  gemm_bt<float, 2, false><<<dim3(512), 256, 0, stream>>>(
      AO, AO, AO, Wob, Wob, Wob, bo, bo, bo, out, out, out, 1.0f, 1.0f, 1.0f);
}

// Round 19
// 138.011 us; speedup vs baseline: 1.4057x; 1.0051x over previous
//
#include <hip/hip_runtime.h>
#include <cstdint>
#include <cstddef>

#define TSEQ 2048
#define DMOD 1024
#define NHEAD 16
#define NBATCH 2
#define MT (NBATCH * TSEQ)
#define LOG2E 1.44269504088896340736f

typedef __attribute__((ext_vector_type(8))) __bf16 bf16x8;
typedef __attribute__((ext_vector_type(4))) float f32x4;
typedef __attribute__((ext_vector_type(8))) unsigned short u16x8;
typedef __attribute__((ext_vector_type(4))) unsigned short u16x4;
typedef __attribute__((ext_vector_type(4))) uint32_t u32x4;

__device__ __forceinline__ unsigned short f2bf(float f) {
  uint32_t u = __builtin_bit_cast(uint32_t, f);
  u += 0x7fffu + ((u >> 16) & 1u);   // RNE (inputs finite)
  return (unsigned short)(u >> 16);
}

__device__ __forceinline__ uint32_t cvt_pk_bf16(float a, float b) {
  uint32_t r;
  asm("v_cvt_pk_bf16_f32 %0, %1, %2" : "=v"(r) : "v"(a), "v"(b));
  return r;
}

__device__ __forceinline__ void gload_lds16(const void* g, const void* l) {
  auto gp = (const __attribute__((address_space(1))) uint32_t*)((uintptr_t)g);
  auto lp = (__attribute__((address_space(3))) uint32_t*)((uintptr_t)l);
  __builtin_amdgcn_global_load_lds(gp, lp, 16, 0, 0);
}

// ------- merged: weight fp32->bf16 cvt (blocks 0..4095) + mask expand ------
__global__ __launch_bounds__(256) void cvt_wm(const float* __restrict__ w0,
                                              const float* __restrict__ w1,
                                              const float* __restrict__ w2,
                                              const float* __restrict__ w3,
                                              const int* __restrict__ m,
                                              unsigned short* __restrict__ dw,
                                              uint32_t* __restrict__ mx) {
  const int bx = blockIdx.x;
  if (bx < 4096) {
    const size_t idx = ((size_t)bx * 256 + threadIdx.x) * 4;   // 4 weights x 1M elems
    const int wsel = (int)(idx >> 20);
    const float* s = wsel == 0 ? w0 : (wsel == 1 ? w1 : (wsel == 2 ? w2 : w3));
    const float4 t = *(const float4*)(s + (idx & 0xFFFFFu));
    u16x4 o;
    o[0] = f2bf(t.x); o[1] = f2bf(t.y); o[2] = f2bf(t.z); o[3] = f2bf(t.w);
    *(u16x4*)(dw + idx) = o;
  } else {
    const size_t W = (size_t)(bx - 4096) * 256 + threadIdx.x;  // < 2*T*16*32
    const int hi = (int)((W >> 3) & 3), ct = (int)(W & 7);
    const size_t bqkt = W >> 5;
    const int kt = (int)(bqkt & 15);
    const size_t bq = bqkt >> 4;
    const int4 mm = *(const int4*)(m + bq * TSEQ + kt * 128 + ct * 16 + hi * 4);
    const uint32_t o = (mm.x ? 0xFFu : 0u) | (mm.y ? 0xFF00u : 0u) |
                       (mm.z ? 0xFF0000u : 0u) | (mm.w ? 0xFF000000u : 0u);
    mx[W] = o;
  }
}

// ---------------- GEMM: C = A[M x 1024] * W[1024x1024]^T + bias, *scale ----
// BK=64 (round-15 config, frozen): 32 MFMA/barrier, XOR-swizzled LDS.
__device__ __forceinline__ void store_c(unsigned short* C, size_t idx, float v) { C[idx] = f2bf(v); }
__device__ __forceinline__ void store_c(float* C, size_t idx, float v) { C[idx] = v; }

template <typename OT, int MF, bool AF32>
__global__ __launch_bounds__(256) void gemm_bt(const void* __restrict__ A0v,
                                               const void* __restrict__ A1v,
                                               const void* __restrict__ A2v,
                                               const unsigned short* __restrict__ W0,
                                               const unsigned short* __restrict__ W1,
                                               const unsigned short* __restrict__ W2,
                                               const float* __restrict__ b0,
                                               const float* __restrict__ b1,
                                               const float* __restrict__ b2,
                                               OT* __restrict__ C0, OT* __restrict__ C1, OT* __restrict__ C2,
                                               float s0, float s1, float s2) {
  constexpr int BM = MF * 32;
  constexpr int NX = 4096 / BM;          // x-tiles per z
  const int nb = gridDim.x, per = nb >> 3, bid = blockIdx.x;
  const int swz = (bid & 7) * per + (bid >> 3);
  const int z = swz / (NX * 8);
  const int rem = swz % (NX * 8);
  const int m0 = (rem >> 3) * BM, n0 = (rem & 7) * 128;

  const void* Av = z == 0 ? A0v : (z == 1 ? A1v : A2v);
  const unsigned short* Bw = z == 0 ? W0 : (z == 1 ? W1 : W2);
  const float* bias = z == 0 ? b0 : (z == 1 ? b1 : b2);
  OT* C = z == 0 ? C0 : (z == 1 ? C1 : C2);
  const float scale = z == 0 ? s0 : (z == 1 ? s1 : s2);

  __shared__ alignas(16) unsigned short As[2][BM * 64];    // [row][64] swizzled
  __shared__ alignas(16) unsigned short Bs[2][128 * 64];   // [row][64] swizzled
  const int tid = threadIdx.x;
  const int wid = tid >> 6;
  const int lane = tid & 63;
  const int lo = lane & 15, hi = lane >> 4;
  const int wr = wid >> 1, wc = wid & 1;
  f32x4 acc[MF][4] = {};

  float4 fa[MF][2];   // A reg-staging (AF32 only)

  auto loadA = [&](int k0) {
    if constexpr (AF32) {
#pragma unroll
      for (int j = 0; j < MF; ++j) {
        const int chunk = j * 256 + tid;
        const int row = chunk >> 3, cl = (chunk & 7) ^ (row & 7);
        const float* p = (const float*)Av + (size_t)(m0 + row) * DMOD + k0 + cl * 8;
        fa[j][0] = *(const float4*)p;
        fa[j][1] = *(const float4*)(p + 4);
      }
    }
  };
  auto writeA = [&](int buf) {
    if constexpr (AF32) {
#pragma unroll
      for (int j = 0; j < MF; ++j) {
        const int chunk = j * 256 + tid;
        u32x4 o;
        o[0] = cvt_pk_bf16(fa[j][0].x, fa[j][0].y);
        o[1] = cvt_pk_bf16(fa[j][0].z, fa[j][0].w);
        o[2] = cvt_pk_bf16(fa[j][1].x, fa[j][1].y);
        o[3] = cvt_pk_bf16(fa[j][1].z, fa[j][1].w);
        *(u32x4*)((char*)As + buf * (BM * 128) + chunk * 16) = o;
      }
    }
  };
  auto stage = [&](int buf, int k0) {
    if constexpr (!AF32) {
#pragma unroll
      for (int i = 0; i < MF; ++i) {
        const int chunk = i * 256 + tid;
        const int row = chunk >> 3, cl = (chunk & 7) ^ (row & 7);
        gload_lds16((const unsigned short*)Av + (size_t)(m0 + row) * DMOD + k0 + cl * 8,
                    (const char*)As + buf * (BM * 128) + chunk * 16);
      }
    }
#pragma unroll
    for (int i = 0; i < 4; ++i) {
      const int chunk = i * 256 + tid;
      const int row = chunk >> 3, cl = (chunk & 7) ^ (row & 7);
      gload_lds16(Bw + (size_t)(n0 + row) * DMOD + k0 + cl * 8,
                  (const char*)Bs + buf * 16384 + chunk * 16);
    }
  };

  loadA(0);
  writeA(0);
  stage(0, 0);
  __syncthreads();    // K-step 0 landed

  for (int k0 = 0; k0 < DMOD; k0 += 64) {
    const int cur = (k0 >> 6) & 1;
    const bool more = k0 + 64 < DMOD;
    if (more) { loadA(k0 + 64); stage(cur ^ 1, k0 + 64); }

#pragma unroll
    for (int kk = 0; kk < 2; ++kk) {
      bf16x8 af[MF], bfr[4];
#pragma unroll
      for (int m = 0; m < MF; ++m) {
        const int row = wr * (MF * 16) + m * 16 + lo;
        af[m] = *(const bf16x8*)((const char*)As + cur * (BM * 128) +
                                 row * 128 + (((kk * 4 + hi) ^ (lo & 7)) * 16));
      }
#pragma unroll
      for (int n = 0; n < 4; ++n) {
        const int row = wc * 64 + n * 16 + lo;
        bfr[n] = *(const bf16x8*)((const char*)Bs + cur * 16384 +
                                  row * 128 + (((kk * 4 + hi) ^ (lo & 7)) * 16));
      }
#pragma unroll
      for (int m = 0; m < MF; ++m)
#pragma unroll
        for (int n = 0; n < 4; ++n)
          acc[m][n] = __builtin_amdgcn_mfma_f32_16x16x32_bf16(af[m], bfr[n], acc[m][n], 0, 0, 0);
    }

    if (more) writeA(cur ^ 1);
    __syncthreads();
  }

#pragma unroll
  for (int n = 0; n < 4; ++n) {
    const int col = n0 + wc * 64 + n * 16 + lo;
    const float bv = bias[col];
#pragma unroll
    for (int m = 0; m < MF; ++m) {
      const int row = m0 + wr * (MF * 16) + m * 16 + hi * 4;
#pragma unroll
      for (int r = 0; r < 4; ++r)
        store_c(C, (size_t)(row + r) * DMOD + col, (acc[m][n][r] + bv) * scale);
    }
  }
}

// ---------------- V transpose + nu-permute: Vp[B*T][D] -> Vt'[...][nu(t)] ---
__global__ __launch_bounds__(256) void transpose_v(const unsigned short* __restrict__ Vp,
                                                   unsigned short* __restrict__ Vt) {
  __shared__ alignas(16) unsigned short tile[64][72];
  const int tid = threadIdx.x;
  const int bt0 = blockIdx.x * 64;
  const int h = blockIdx.y;
  const int b = bt0 >> 11;
  const int t0 = bt0 & (TSEQ - 1);
#pragma unroll
  for (int i = 0; i < 2; ++i) {
    const int chunk = i * 256 + tid;
    const int row = chunk >> 3, c = chunk & 7;
    *(uint4*)((char*)&tile[row][0] + c * 16) =
        *(const uint4*)(Vp + (size_t)(bt0 + row) * DMOD + h * 64 + c * 8);
  }
  __syncthreads();
#pragma unroll
  for (int i = 0; i < 2; ++i) {
    const int chunk = i * 256 + tid;
    const int dk = chunk >> 3, c = chunk & 7;
    u16x8 o;
#pragma unroll
    for (int j = 0; j < 8; ++j) {
      const int x = c * 8 + j;   // nu index within the 64-tile
      const int kl = (x & 32) | ((x & 24) >> 1) | ((x & 4) << 2) | (x & 3);
      o[j] = tile[kl][dk];
    }
    *(u16x8*)(Vt + ((size_t)(b * NHEAD + h) * 64 + dk) * TSEQ + t0 + c * 8) = o;
  }
}

// -------- flash attention: T15 @ KVBLK=64 — QK(t+1) || exp/pack/PV(t) ------
// Score state sA[4]+sB[4] = 32 VGPR (same as the single-buffered KVBLK=128
// kernel), so no spill. K 2-buf, V 3-buf = 40 KB LDS. Named arrays, literal
// indices only (rule #20). Masks: one uint4 pair per 128-group; even sub-tile
// uses the first uint4, odd the second (same byte semantics as before).
__global__ __launch_bounds__(512, 4) void attn_kernel(const unsigned short* __restrict__ Qp,
                                                      const unsigned short* __restrict__ Kp,
                                                      const unsigned short* __restrict__ Vt,
                                                      const uint32_t* __restrict__ mx,
                                                      unsigned short* __restrict__ AO) {
  __shared__ alignas(16) unsigned short Ks[2][64 * 64];   // [kcol][d] chunk-XOR swizzled
  __shared__ alignas(16) unsigned short Vs[3][64 * 64];   // [dk][nu]  chunk-XOR swizzled
  const int tid = threadIdx.x;
  const int w = tid >> 6, lane = tid & 63;
  const int lo = lane & 15, hi = lane >> 4;
  const int f = blockIdx.x;                 // 0..511, XCD swizzle
  const int swz = (f & 7) * 64 + (f >> 3);
  const int q0 = (swz & 15) * 128;
  const int h = (swz >> 4) & 15;
  const int b = swz >> 8;

  bf16x8 qf[2];
  {
    const unsigned short* qsrc =
        Qp + (size_t)(b * TSEQ + q0 + w * 16 + lo) * DMOD + h * 64 + hi * 8;
    qf[0] = *(const bf16x8*)qsrc;
    qf[1] = *(const bf16x8*)(qsrc + 32);
  }

  bf16x8 ones;
  {
    u32x4 od;
    od[0] = 0x3F803F80u; od[1] = 0x3F803F80u; od[2] = 0x3F803F80u; od[3] = 0x3F803F80u;
    ones = __builtin_bit_cast(bf16x8, od);
  }

  f32x4 o_acc[4] = {};
  f32x4 l_acc = {};

  const size_t kbase = (size_t)(b * TSEQ) * DMOD + h * 64;
  const size_t vbase = (size_t)(b * NHEAD + h) * 64 * TSEQ;

  // staging: 512 threads cover 512 K-chunks + 512 V-chunks (1 each)
  const unsigned short* kp0 = Kp + kbase + (size_t)(tid >> 3) * DMOD + ((tid & 7) ^ ((tid >> 3) & 7)) * 8;
  const unsigned short* vp0 = Vt + vbase + (size_t)(tid >> 3) * TSEQ + ((tid & 7) ^ ((tid >> 3) & 7)) * 8;
  const uint32_t* mp = mx + (size_t)(b * TSEQ + q0 + w * 16 + lo) * 512 + hi * 8;
  const int wb0 = tid * 16;

  int koffA[4], koffB[4];
#pragma unroll
  for (int ct = 0; ct < 4; ++ct) {
    const int kcol = ct * 16 + lo;
    koffA[ct] = kcol * 128 + ((hi ^ (kcol & 7)) * 16);
    koffB[ct] = kcol * 128 + (((4 + hi) ^ (kcol & 7)) * 16);
  }
  int voff[4][2];
#pragma unroll
  for (int vt = 0; vt < 4; ++vt) {
    const int dk = vt * 16 + lo;
#pragma unroll
    for (int c = 0; c < 2; ++c) voff[vt][c] = dk * 128 + (((c * 4 + hi) ^ (dk & 7)) * 16);
  }

  auto stage = [&](int kbuf, int vbuf) {
    gload_lds16(kp0, (const char*)Ks[kbuf] + wb0);
    gload_lds16(vp0, (const char*)Vs[vbuf] + wb0);
    kp0 += (size_t)64 * DMOD;
    vp0 += 64;
  };

  const uint32_t selA = 0x01010000u, selB = 0x03030202u;

#define QK_TILE(S, KSB) do {                                                  \
    const char* _k = (KSB);                                                   \
    __builtin_amdgcn_s_setprio(1);                                            \
    _Pragma("unroll")                                                         \
    for (int ct = 0; ct < 4; ++ct) {                                          \
      bf16x8 kf0 = *(const bf16x8*)(_k + koffA[ct]);                          \
      bf16x8 kf1 = *(const bf16x8*)(_k + koffB[ct]);                          \
      f32x4 zz = {0.f, 0.f, 0.f, 0.f};                                       \
      S[ct] = __builtin_amdgcn_mfma_f32_16x16x32_bf16(kf0, qf[0], zz, 0, 0, 0);    \
      S[ct] = __builtin_amdgcn_mfma_f32_16x16x32_bf16(kf1, qf[1], S[ct], 0, 0, 0); \
    }                                                                         \
    __builtin_amdgcn_s_setprio(0);                                            \
  } while (0)

#define EXPPV_TILE(S, M, VSB) do {                                            \
    const char* _v = (VSB);                                                   \
    _Pragma("unroll")                                                         \
    for (int ct = 0; ct < 4; ++ct) {                                          \
      S[ct][0] = __builtin_exp2f(S[ct][0]);                                   \
      S[ct][1] = __builtin_exp2f(S[ct][1]);                                   \
      S[ct][2] = __builtin_exp2f(S[ct][2]);                                   \
      S[ct][3] = __builtin_exp2f(S[ct][3]);                                   \
    }                                                                         \
    bf16x8 pf[2];                                                             \
    _Pragma("unroll")                                                         \
    for (int c = 0; c < 2; ++c) {                                             \
      const uint32_t We = c == 0 ? M.x : M.z;                                 \
      const uint32_t Wo = c == 0 ? M.y : M.w;                                 \
      u32x4 pd;                                                               \
      pd[0] = cvt_pk_bf16(S[2 * c][0], S[2 * c][1]) & __builtin_amdgcn_perm(We, We, selA); \
      pd[1] = cvt_pk_bf16(S[2 * c][2], S[2 * c][3]) & __builtin_amdgcn_perm(We, We, selB); \
      pd[2] = cvt_pk_bf16(S[2 * c + 1][0], S[2 * c + 1][1]) & __builtin_amdgcn_perm(Wo, Wo, selA); \
      pd[3] = cvt_pk_bf16(S[2 * c + 1][2], S[2 * c + 1][3]) & __builtin_amdgcn_perm(Wo, Wo, selB); \
      pf[c] = __builtin_bit_cast(bf16x8, pd);                                 \
    }                                                                         \
    __builtin_amdgcn_s_setprio(1);                                            \
    _Pragma("unroll")                                                         \
    for (int vt = 0; vt < 4; ++vt) {                                          \
      _Pragma("unroll")                                                       \
      for (int c = 0; c < 2; ++c) {                                           \
        bf16x8 vf = *(const bf16x8*)(_v + voff[vt][c]);                       \
        o_acc[vt] = __builtin_amdgcn_mfma_f32_16x16x32_bf16(pf[c], vf, o_acc[vt], 0, 0, 0); \
      }                                                                       \
    }                                                                         \
    _Pragma("unroll")                                                         \
    for (int c = 0; c < 2; ++c)                                               \
      l_acc = __builtin_amdgcn_mfma_f32_16x16x32_bf16(pf[c], ones, l_acc, 0, 0, 0); \
    __builtin_amdgcn_s_setprio(0);                                            \
  } while (0)

  const int NT = TSEQ / 64;   // 32 (even)
  f32x4 sA[4], sB[4];
  uint4 gE, gF, nE, nF;       // current / next 128-group mask halves

  // prologue
  gE = *(const uint4*)mp; gF = *(const uint4*)(mp + 4); mp += 32;
  stage(0, 0);               // tile 0
  __syncthreads();           // tile 0 landed
  stage(1, 1);               // tile 1 (in flight)
  QK_TILE(sA, (const char*)Ks[0]);
  __syncthreads();           // tile 1 landed

  for (int kt = 0; kt < NT; kt += 2) {
    // load next 128-group's masks (consumed next iteration)
    if (kt + 2 < NT) { nE = *(const uint4*)mp; nF = *(const uint4*)(mp + 4); mp += 32; }

    // phase A: QK(kt+1) || EXPPV(kt)  [kt even -> mask gE]
    if (kt + 2 < NT) stage(kt & 1, (kt + 2) % 3);
    QK_TILE(sB, (const char*)Ks[(kt + 1) & 1]);
    EXPPV_TILE(sA, gE, (const char*)Vs[kt % 3]);
    __syncthreads();         // tile kt+2 landed

    // phase B: QK(kt+2) || EXPPV(kt+1)  [kt+1 odd -> mask gF]
    if (kt + 3 < NT) stage((kt + 1) & 1, (kt + 3) % 3);
    if (kt + 2 < NT) QK_TILE(sA, (const char*)Ks[(kt + 2) & 1]);
    EXPPV_TILE(sB, gF, (const char*)Vs[(kt + 1) % 3]);
    __syncthreads();         // tile kt+3 landed
    gE = nE; gF = nF;
  }

#undef QK_TILE
#undef EXPPV_TILE

#pragma unroll
  for (int r = 0; r < 4; ++r) {
    const float rl = 1.0f / l_acc[r];
    const size_t orow = (size_t)(b * TSEQ + q0 + w * 16 + hi * 4 + r) * DMOD + h * 64;
#pragma unroll
    for (int vt = 0; vt < 4; ++vt)
      AO[orow + vt * 16 + lo] = f2bf(o_acc[vt][r] * rl);
  }
}

// ---------------- launcher -------------------------------------------------
extern "C" void kernel_launch(void* const* d_in, const int* in_sizes, int n_in,
                              void* d_out, int out_size, void* d_ws, size_t ws_size,
                              hipStream_t stream) {
  const float* q  = (const float*)d_in[0];
  const float* k  = (const float*)d_in[1];
  const float* v  = (const float*)d_in[2];
  const int* mask = (const int*)d_in[3];
  const float* Wq = (const float*)d_in[4];
  const float* bq = (const float*)d_in[5];
  const float* Wk = (const float*)d_in[6];
  const float* bk = (const float*)d_in[7];
  const float* Wv = (const float*)d_in[8];
  const float* bv = (const float*)d_in[9];
  const float* Wo = (const float*)d_in[10];
  const float* bo = (const float*)d_in[11];
  float* out = (float*)d_out;

  char* ws = (char*)d_ws;
  const size_t SZ_BT = (size_t)MT * DMOD * 2;   // 8 MiB

  unsigned short* Qp  = (unsigned short*)(ws + 0);
  unsigned short* Kp  = (unsigned short*)(ws + SZ_BT);
  unsigned short* Vp  = (unsigned short*)(ws + 2 * SZ_BT);
  unsigned short* Vt  = (unsigned short*)(ws + 3 * SZ_BT);
  unsigned short* Wqb = (unsigned short*)(ws + 4 * SZ_BT);          // 4 weights, 8 MiB
  uint32_t*       mx  = (uint32_t*)(ws + 5 * SZ_BT);                // 8.39 MiB
  unsigned short* AO  = Vp;   // Vp dead after transpose_v
  unsigned short* Wob = Wqb + 3 * DMOD * DMOD;

  const int nW = DMOD * DMOD;

  // weights cvt + mask expand, one launch (both memory-bound streams)
  cvt_wm<<<dim3(4096 + (NBATCH * TSEQ * 16 * 32) / 256), 256, 0, stream>>>(
      Wq, Wk, Wv, Wo, mask, Wqb, mx);

  const float qs = 0.125f * LOG2E;
  // QKV projections: fp32 A read directly from inputs, cvt fused into staging
  gemm_bt<unsigned short, 4, true><<<dim3(768), 256, 0, stream>>>(
      q, k, v, Wqb, Wqb + nW, Wqb + 2 * nW, bq, bk, bv, Qp, Kp, Vp, qs, 1.0f, 1.0f);

  transpose_v<<<dim3(MT / 64, NHEAD), 256, 0, stream>>>(Vp, Vt);

  attn_kernel<<<dim3(512), 512, 0, stream>>>(Qp, Kp, Vt, mx, AO);

  gemm_bt<float, 2, false><<<dim3(512), 256, 0, stream>>>(
      AO, AO, AO, Wob, Wob, Wob, bo, bo, bo, out, out, out, 1.0f, 1.0f, 1.0f);
}